// Round 16
// baseline (716.900 us; speedup 1.0000x reference)
//
#include <hip/hip_runtime.h>
#include <hip/hip_bf16.h>
#include <type_traits>

using bf16 = __hip_bfloat16;
typedef short v8s __attribute__((ext_vector_type(8)));
typedef float v4f __attribute__((ext_vector_type(4)));

#define DEV __device__ __forceinline__

constexpr float SCALE_ = 0.07216878364870322f;  // (128+64)^-0.5

DEV unsigned short bfu(float f) {
  bf16 h = __float2bfloat16(f);
  return __builtin_bit_cast(unsigned short, h);
}
DEV float b2f(short u) {
  unsigned int x = ((unsigned int)(unsigned short)u) << 16;
  return __builtin_bit_cast(float, x);
}

DEV void g2lds16(const void* g, void* l) {
  __builtin_amdgcn_global_load_lds(
      (const __attribute__((address_space(1))) unsigned int*)g,
      (__attribute__((address_space(3))) unsigned int*)l, 16, 0, 0);
}

// ---------------- elementwise / prep kernels ----------------

__global__ void cast_kernel(const float* __restrict__ in, bf16* __restrict__ out, int n4) {
  int i = blockIdx.x * 256 + threadIdx.x;
  int stride = gridDim.x * 256;
  for (; i < n4; i += stride) {
    float4 v = ((const float4*)in)[i];
    ushort4 u;
    u.x = bfu(v.x); u.y = bfu(v.y); u.z = bfu(v.z); u.w = bfu(v.w);
    ((ushort4*)out)[i] = u;
  }
}

// wkv_a (576,4096) f32 -> (640,4096) bf16 zero-padded
__global__ void cast_pad_kernel(const float* __restrict__ in, bf16* __restrict__ out) {
  int i = blockIdx.x * 256 + threadIdx.x;  // 655360 float4 groups
  float4 v = make_float4(0.f, 0.f, 0.f, 0.f);
  if (i < 589824) v = ((const float4*)in)[i];  // 576*4096/4
  ushort4 u;
  u.x = bfu(v.x); u.y = bfu(v.y); u.z = bfu(v.z); u.w = bfu(v.w);
  ((ushort4*)out)[i] = u;
}

// wkv_b nope-part transpose, coalesced 8x8 reg-block:
// out[h][c][d] = wkvb[(h*256+d)*512 + c], d<128, c<512.
__global__ void wkvbt_kernel(const float* __restrict__ wkvb, bf16* __restrict__ out) {
  int gid = blockIdx.x * 256 + threadIdx.x;  // 32*16*64
  int c8 = (gid & 63) * 8;
  int d8 = ((gid >> 6) & 15) * 8;
  int h = gid >> 10;
  float4 a[8][2];
#pragma unroll
  for (int r = 0; r < 8; ++r) {
    const float* p = wkvb + ((long)(h * 256 + d8 + r)) * 512 + c8;
    a[r][0] = *(const float4*)p;
    a[r][1] = *(const float4*)(p + 4);
  }
#pragma unroll
  for (int cc = 0; cc < 8; ++cc) {
    v8s o;
#pragma unroll
    for (int r = 0; r < 8; ++r) {
      float f = (cc < 4) ? ((const float*)&a[r][0])[cc] : ((const float*)&a[r][1])[cc - 4];
      o[r] = (short)bfu(f);
    }
    *(v8s*)(out + (long)h * 65536 + (c8 + cc) * 128 + d8) = o;
  }
}

// wkv_b v-part: out[h*128+d][c] = wkv_b[(h*256+128+d)][c], bf16
__global__ void wkvbv_kernel(const float* __restrict__ wkvb, bf16* __restrict__ out) {
  int i = blockIdx.x * 256 + threadIdx.x;  // 524288 float4 groups
  int c4 = i & 127, d = (i >> 7) & 127, h = i >> 14;
  float4 v = *(const float4*)(wkvb + ((long)(h * 256 + 128 + d)) * 512 + c4 * 4);
  ushort4 u;
  u.x = bfu(v.x); u.y = bfu(v.y); u.z = bfu(v.z); u.w = bfu(v.w);
  *(ushort4*)(out + ((long)(h * 128 + d)) * 512 + c4 * 4) = u;
}

__global__ void freqs_kernel(float* __restrict__ cosb, float* __restrict__ sinb) {
  int t = blockIdx.x * 256 + threadIdx.x;  // 2048*32
  int s = t >> 5, i = t & 31;
  float inv = powf(10000.0f, -(float)(2 * i) / 64.0f);
  float f = (float)s * inv;
  cosb[t] = cosf(f);
  sinb[t] = sinf(f);
}

// rmsnorm over bf16 rows, f32 weight, bf16 out
__global__ void rmsnorm_bf_kernel(const bf16* __restrict__ in, const float* __restrict__ w,
                                  bf16* __restrict__ out, int L, int ldin, int ldout) {
  int row = blockIdx.x;
  const bf16* x = in + (long)row * ldin;
  int L8 = L >> 3;
  float ss = 0.f;
  for (int i = threadIdx.x; i < L8; i += 256) {
    v8s v = *(const v8s*)(x + i * 8);
#pragma unroll
    for (int j = 0; j < 8; ++j) { float f = b2f(v[j]); ss += f * f; }
  }
#pragma unroll
  for (int d = 1; d < 64; d <<= 1) ss += __shfl_xor(ss, d);
  __shared__ float red[4];
  if ((threadIdx.x & 63) == 0) red[threadIdx.x >> 6] = ss;
  __syncthreads();
  float r = rsqrtf((red[0] + red[1] + red[2] + red[3]) / (float)L + 1e-6f);
  bf16* o = out + (long)row * ldout;
  for (int i = threadIdx.x; i < L8; i += 256) {
    v8s v = *(const v8s*)(x + i * 8);
    v8s u;
#pragma unroll
    for (int j = 0; j < 8; ++j)
      u[j] = (short)bfu(b2f(v[j]) * r * w[i * 8 + j]);
    *(v8s*)(o + i * 8) = u;
  }
}

// k_pe rope: qa_kv (S,2176) bf16 cols 2048..2111 -> keff (S,576) cols 512..575
__global__ void rope_kpe_kernel(const bf16* __restrict__ qakv, const float* __restrict__ cosb,
                                const float* __restrict__ sinb, bf16* __restrict__ keff) {
  int t = blockIdx.x * 256 + threadIdx.x;  // 2048*32
  int s = t >> 5, i = t & 31;
  const bf16* p = qakv + (long)s * 2176 + 2048;
  float x0 = __bfloat162float(p[2 * i]), x1 = __bfloat162float(p[2 * i + 1]);
  float c = cosb[t], sn = sinb[t];
  bf16* o = keff + (long)s * 576 + 512;
  o[2 * i] = __float2bfloat16(x0 * c - x1 * sn);
  o[2 * i + 1] = __float2bfloat16(x0 * sn + x1 * c);
}

// q_pe rope: qf (S,32,192) cols 128..191 -> qeff (S,32,576) cols 512..575
__global__ void rope_q_kernel(const bf16* __restrict__ qf, const float* __restrict__ cosb,
                              const float* __restrict__ sinb, bf16* __restrict__ qeff) {
  int t = blockIdx.x * 256 + threadIdx.x;  // S*H*32
  int i = t & 31, h = (t >> 5) & 31, s = t >> 10;
  const bf16* p = qf + (long)s * 6144 + h * 192 + 128;
  float x0 = __bfloat162float(p[2 * i]), x1 = __bfloat162float(p[2 * i + 1]);
  float c = cosb[s * 32 + i], sn = sinb[s * 32 + i];
  bf16* o = qeff + (long)s * 18432 + h * 576 + 512;
  o[2 * i] = __float2bfloat16(x0 * c - x1 * sn);
  o[2 * i + 1] = __float2bfloat16(x0 * sn + x1 * c);
}

// vT[c][t] = keff[t][c] for c<512 (latent V, post-rmsnorm). 8x8 reg transpose.
__global__ void vtrans_kernel(const bf16* __restrict__ keff, bf16* __restrict__ vT) {
  int gid = blockIdx.x * 256 + threadIdx.x;  // 16384 threads
  int t8 = (gid & 255) * 8, c8 = (gid >> 8) * 8;
  v8s in[8];
#pragma unroll
  for (int r = 0; r < 8; ++r)
    in[r] = *(const v8s*)(keff + (long)(t8 + r) * 576 + c8);
#pragma unroll
  for (int cc = 0; cc < 8; ++cc) {
    v8s o;
#pragma unroll
    for (int r = 0; r < 8; ++r) o[r] = in[r][cc];
    *(v8s*)(vT + (long)(c8 + cc) * 2048 + t8) = o;
  }
}

// ---------------- GEMM: C = A @ B^T, A (M,K) bf16, B (N,K) bf16 ----------------
template <typename OutT>
__global__ __launch_bounds__(256, 3) void gemm_bt(
    const bf16* __restrict__ A, const bf16* __restrict__ B, OutT* __restrict__ C,
    int K, int lda, int ldb, int ldc, long sA, long sB, long sC) {
  __shared__ bf16 lA[4096];
  __shared__ bf16 lB[4096];
  const int tid = threadIdx.x;
  const int lane = tid & 63;
  const int w = tid >> 6, wm = w >> 1, wn = w & 1;
  const int r16 = lane & 15, kg = (lane >> 4) << 3;
  const int arow = tid >> 2, acol = (tid & 3) << 3;
  const bf16* Ab = A + (long)blockIdx.z * sA + (long)blockIdx.y * 128 * lda;
  const bf16* Bb = B + (long)blockIdx.z * sB + (long)blockIdx.x * 128 * ldb;
  v4f acc[4][4] = {};
  for (int k0 = 0; k0 < K; k0 += 32) {
    __syncthreads();
#pragma unroll
    for (int i = 0; i < 2; ++i) {
      g2lds16(Ab + (long)(i * 64 + arow) * lda + (k0 + acol), &lA[i * 2048 + w * 512]);
      g2lds16(Bb + (long)(i * 64 + arow) * ldb + (k0 + acol), &lB[i * 2048 + w * 512]);
    }
    __syncthreads();
    v8s af[4], bfr[4];
#pragma unroll
    for (int mi = 0; mi < 4; ++mi)
      af[mi] = *(const v8s*)&lA[(wm * 64 + mi * 16 + r16) * 32 + kg];
#pragma unroll
    for (int ni = 0; ni < 4; ++ni)
      bfr[ni] = *(const v8s*)&lB[(wn * 64 + ni * 16 + r16) * 32 + kg];
    __builtin_amdgcn_s_setprio(1);
#pragma unroll
    for (int mi = 0; mi < 4; ++mi)
#pragma unroll
      for (int ni = 0; ni < 4; ++ni)
        acc[mi][ni] = __builtin_amdgcn_mfma_f32_16x16x32_bf16(af[mi], bfr[ni], acc[mi][ni], 0, 0, 0);
    __builtin_amdgcn_s_setprio(0);
  }
  OutT* Cb = C + (long)blockIdx.z * sC + (long)(blockIdx.y * 128) * ldc + blockIdx.x * 128;
  const int cr = (lane >> 4) << 2;
#pragma unroll
  for (int mi = 0; mi < 4; ++mi)
#pragma unroll
    for (int ni = 0; ni < 4; ++ni)
#pragma unroll
      for (int j = 0; j < 4; ++j) {
        long idx = (long)(wm * 64 + mi * 16 + cr + j) * ldc + wn * 64 + ni * 16 + r16;
        float v = acc[mi][ni][j];
        if constexpr (std::is_same<OutT, float>::value) Cb[idx] = v;
        else Cb[idx] = __float2bfloat16(v);
      }
}

// ---------------- GEMM K=128 one-shot: C = A @ B^T, single staging pass ----
__global__ __launch_bounds__(256, 2) void gemm_k128(
    const bf16* __restrict__ A, const bf16* __restrict__ B, bf16* __restrict__ C,
    int lda, int ldb, int ldc, long sA, long sB, long sC) {
  __shared__ bf16 lA[16384];
  __shared__ bf16 lB[16384];
  const int tid = threadIdx.x;
  const int lane = tid & 63;
  const int w = tid >> 6, wm = w >> 1, wn = w & 1;
  const int r16 = lane & 15, hi = lane >> 4;
  const bf16* Ab = A + (long)blockIdx.z * sA + (long)blockIdx.y * 128 * lda;
  const bf16* Bb = B + (long)blockIdx.z * sB + (long)blockIdx.x * 128 * ldb;
#pragma unroll
  for (int it = 0; it < 8; ++it) {
    int D = it * 256 + tid;       // slot 0..2047; 16 slots (256B) per row
    int row = D >> 4, sl = D & 15;
    int gs = sl ^ (row & 7);      // pre-swizzled source slot
    g2lds16(Ab + (long)row * lda + gs * 8, (char*)lA + (it * 256 + w * 64) * 16);
    g2lds16(Bb + (long)row * ldb + gs * 8, (char*)lB + (it * 256 + w * 64) * 16);
  }
  __syncthreads();
  v4f acc[4][4] = {};
#pragma unroll
  for (int kk = 0; kk < 4; ++kk) {
    v8s af[4], bfr[4];
#pragma unroll
    for (int mi = 0; mi < 4; ++mi) {
      int r = wm * 64 + mi * 16 + r16;
      af[mi] = *(const v8s*)((const char*)lA + (r * 16 + ((kk * 4 + hi) ^ (r & 7))) * 16);
    }
#pragma unroll
    for (int ni = 0; ni < 4; ++ni) {
      int r = wn * 64 + ni * 16 + r16;
      bfr[ni] = *(const v8s*)((const char*)lB + (r * 16 + ((kk * 4 + hi) ^ (r & 7))) * 16);
    }
    __builtin_amdgcn_s_setprio(1);
#pragma unroll
    for (int mi = 0; mi < 4; ++mi)
#pragma unroll
      for (int ni = 0; ni < 4; ++ni)
        acc[mi][ni] = __builtin_amdgcn_mfma_f32_16x16x32_bf16(af[mi], bfr[ni], acc[mi][ni], 0, 0, 0);
    __builtin_amdgcn_s_setprio(0);
  }
  bf16* Cb = C + (long)blockIdx.z * sC + (long)(blockIdx.y * 128) * ldc + blockIdx.x * 128;
  const int cr = hi << 2;
#pragma unroll
  for (int mi = 0; mi < 4; ++mi)
#pragma unroll
    for (int ni = 0; ni < 4; ++ni)
#pragma unroll
      for (int j = 0; j < 4; ++j) {
        long idx = (long)(wm * 64 + mi * 16 + cr + j) * ldc + wn * 64 + ni * 16 + r16;
        Cb[idx] = __float2bfloat16(acc[mi][ni][j]);
      }
}

// ---------------- causal flash attention (swapped-QK, col-split PV) ----
// grid (32 heads, 24 units), 512 thr, 8 waves, Q-tile 128, KV-split balanced.
// QK + softmax: wave w owns q rows [128qt+16w,+16) (unchanged). NEW: P and
// alpha go through LDS (pl [128][40] pad, alf[128]); PV ownership flips to
// column-slices: wave w computes O[all 128 q][cols w*64..+64], so the V tile
// is read ONCE per chunk (was 8x) and the shfl P-redistribution is deleted.
// LDS 80384 B -> still 2 blocks/CU. Same 2 barriers/chunk.
__device__ const signed char U_QT[24] = {15,15,7,14,14,13,13,6,12,12,11,11,5,10,10,9,9,4,8,8,3,2,1,0};
__device__ const signed char U_HF[24] = {0,1,-1,0,1,0,1,-1,0,1,0,1,-1,0,1,0,1,-1,0,1,-1,-1,-1,-1};

__global__ __launch_bounds__(512, 2) void attn_kernel(
    const bf16* __restrict__ qeff, const bf16* __restrict__ keff,
    const bf16* __restrict__ vT, bf16* __restrict__ olat,
    bf16* __restrict__ P1, float* __restrict__ mlb) {
  __shared__ __align__(16) bf16 kl[32 * 576];   // 36864 B
  __shared__ __align__(16) bf16 vl[512 * 32];   // 32768 B
  __shared__ __align__(16) bf16 pl[128 * 40];   // 10240 B (PLD=40: 2-way banks)
  __shared__ __align__(16) float alf[128];      // alpha per q; reused for l
  const int tid = threadIdx.x, lane = tid & 63, w = tid >> 6;
  const int r16 = lane & 15, hi = lane >> 4;
  const int kg = hi << 3, cr = hi << 2;
  const int h = blockIdx.x;
  const int u = blockIdx.y;
  const int qt = U_QT[u];
  const int hf = U_HF[u];
  const int nch = 4 * qt + 4;
  const int kc0 = (hf == 1) ? (nch >> 1) : 0;
  const int kc1 = (hf == 0) ? (nch >> 1) : nch;
  const int qrow = qt * 128 + w * 16 + r16;
  const int rb = r16 & 7;

  const long qbase = (long)qrow * 18432 + h * 576;
  v8s qreg[18];
#pragma unroll
  for (int kk = 0; kk < 18; ++kk)
    qreg[kk] = __builtin_nontemporal_load((const v8s*)(qeff + qbase + kk * 32 + kg));

  v4f acc[32] = {};  // [qb][cfc]: O[q=qb*16+hi*4+j][col=w*64+cfc*16+r16]
  float mrow = -1e30f, lrow = 0.f;

  // staging helpers (16B slots; K: 72 slots/row, V: 4 slots/row)
  auto stageK = [&](int t0) {
#pragma unroll
    for (int it = 0; it < 5; ++it) {
      int D = it * 512 + tid;           // 0..2303 (last iter: waves 0-3 only)
      if (D < 2304) {
        int row = D / 72;
        int gg = D - row * 72;
        int gs = gg ^ (row & 7);        // pre-swizzled source slot
        g2lds16(keff + (long)(t0 + row) * 576 + gs * 8,
                (char*)kl + (it * 512 + w * 64) * 16);
      }
    }
  };
  auto stageV = [&](int t0) {
#pragma unroll
    for (int it = 0; it < 4; ++it) {
      int D = it * 512 + tid;           // 0..2047
      int row = D >> 2;
      int s = (D & 3) ^ ((row >> 1) & 3);
      g2lds16(vT + (long)row * 2048 + t0 + s * 8,
              (char*)vl + (it * 512 + w * 64) * 16);
    }
  };

  stageK(kc0 * 32);
  __syncthreads();

  for (int kc = kc0; kc < kc1; ++kc) {
    const int t0 = kc * 32;
    stageV(t0);  // drains at mid barrier (hidden under QK+softmax)

    // ---- S^T = K Q^T from kl (swizzled b128 reads, 2-way free) ----
    const char* kb = (const char*)kl;
    v4f sf0 = {}, sf1 = {};
    __builtin_amdgcn_s_setprio(1);
#pragma unroll
    for (int kk = 0; kk < 18; ++kk) {
      int so = ((kk * 4 + hi) ^ rb) << 4;
      v8s b0 = *(const v8s*)(kb + r16 * 1152 + so);
      v8s b1 = *(const v8s*)(kb + (16 + r16) * 1152 + so);
      sf0 = __builtin_amdgcn_mfma_f32_16x16x32_bf16(b0, qreg[kk], sf0, 0, 0, 0);
      sf1 = __builtin_amdgcn_mfma_f32_16x16x32_bf16(b1, qreg[kk], sf1, 0, 0, 0);
    }
    __builtin_amdgcn_s_setprio(0);
    // ---- mask + per-lane softmax (q = qrow) ----
    float s0[4], s1[4];
#pragma unroll
    for (int j = 0; j < 4; ++j) { s0[j] = sf0[j] * SCALE_; s1[j] = sf1[j] * SCALE_; }
    if (kc >= 4 * qt) {
#pragma unroll
      for (int j = 0; j < 4; ++j) {
        if (t0 + cr + j > qrow) s0[j] = -1e30f;
        if (t0 + 16 + cr + j > qrow) s1[j] = -1e30f;
      }
    }
    float mx = fmaxf(fmaxf(fmaxf(s0[0], s0[1]), fmaxf(s0[2], s0[3])),
                     fmaxf(fmaxf(s1[0], s1[1]), fmaxf(s1[2], s1[3])));
    mx = fmaxf(mx, __shfl_xor(mx, 16));
    mx = fmaxf(mx, __shfl_xor(mx, 32));
    // defer-max: rescale only when the running max grew by > 8
    float alpha = 1.0f;
    if (!__all(mx <= mrow + 8.0f)) {
      float mn = fmaxf(mrow, mx);
      alpha = __expf(mrow - mn);
      mrow = mn;
      lrow *= alpha;
    }
    float p0[4], p1[4];
#pragma unroll
    for (int j = 0; j < 4; ++j) {
      p0[j] = __expf(s0[j] - mrow);
      p1[j] = __expf(s1[j] - mrow);
    }
    float rs = (p0[0] + p0[1]) + (p0[2] + p0[3]) + (p1[0] + p1[1]) + (p1[2] + p1[3]);
    rs += __shfl_xor(rs, 16);
    rs += __shfl_xor(rs, 32);
    lrow += rs;
    // ---- write P (bf16 pairs) + alpha to LDS ----
    {
      int u0 = (int)((unsigned)bfu(p0[0]) | ((unsigned)bfu(p0[1]) << 16));
      int u1 = (int)((unsigned)bfu(p0[2]) | ((unsigned)bfu(p0[3]) << 16));
      int v0 = (int)((unsigned)bfu(p1[0]) | ((unsigned)bfu(p1[1]) << 16));
      int v1 = (int)((unsigned)bfu(p1[2]) | ((unsigned)bfu(p1[3]) << 16));
      const int q = w * 16 + r16;
      char* prow = (char*)pl + q * 80;
      *(int2*)(prow + hi * 8) = make_int2(u0, u1);          // t = cr..cr+3
      *(int2*)(prow + 32 + hi * 8) = make_int2(v0, v1);     // t = 16+cr..+3
      if (hi == 0) alf[q] = alpha;
    }

    __syncthreads();  // kl/pl/alf ready; stageV drained
    if (kc + 1 < kc1) stageK(t0 + 32);  // overwrite kl; drains at loop-end barrier

    // ---- PV: wave w owns cols w*64..+64 for ALL 128 q ----
    v8s bv[4];
#pragma unroll
    for (int cfc = 0; cfc < 4; ++cfc) {
      const int vrow = w * 64 + cfc * 16 + r16;
      const int vsw = (hi ^ ((vrow >> 1) & 3)) << 4;
      bv[cfc] = *(const v8s*)((const char*)vl + vrow * 64 + vsw);
    }
    __builtin_amdgcn_s_setprio(1);
#pragma unroll
    for (int qb = 0; qb < 8; ++qb) {
      v8s pa = *(const v8s*)((const char*)pl + (qb * 16 + r16) * 80 + hi * 16);
      v4f af4 = *(const v4f*)&alf[qb * 16 + (hi << 2)];
#pragma unroll
      for (int cfc = 0; cfc < 4; ++cfc) {
        v4f a = acc[qb * 4 + cfc];
        a[0] *= af4[0]; a[1] *= af4[1]; a[2] *= af4[2]; a[3] *= af4[3];
        acc[qb * 4 + cfc] = __builtin_amdgcn_mfma_f32_16x16x32_bf16(pa, bv[cfc], a, 0, 0, 0);
      }
    }
    __builtin_amdgcn_s_setprio(0);
    __syncthreads();  // vl/pl/alf reads done; stageK drained -> kl ready
  }
  // ---- epilogue: share l via alf (reused), store ----
  if (hf >= 0 && hi == 0) {
    float* mr = mlb + (((qrow - 1024) << 5) + h) * 4 + hf * 2;
    mr[0] = mrow;
    mr[1] = lrow;
  }
  if (hi == 0) alf[w * 16 + r16] = lrow;
  __syncthreads();
  if (hf < 0) {
#pragma unroll
    for (int qb = 0; qb < 8; ++qb) {
      v4f lf4 = *(const v4f*)&alf[qb * 16 + (hi << 2)];
      float linv0 = 1.0f / lf4[0], linv1 = 1.0f / lf4[1];
      float linv2 = 1.0f / lf4[2], linv3 = 1.0f / lf4[3];
#pragma unroll
      for (int cfc = 0; cfc < 4; ++cfc) {
        const long base = (long)(qt * 128 + qb * 16 + (hi << 2)) * 16384 + h * 512 + w * 64 + cfc * 16 + r16;
        v4f a = acc[qb * 4 + cfc];
        olat[base + 0 * 16384] = __float2bfloat16(a[0] * linv0);
        olat[base + 1 * 16384] = __float2bfloat16(a[1] * linv1);
        olat[base + 2 * 16384] = __float2bfloat16(a[2] * linv2);
        olat[base + 3 * 16384] = __float2bfloat16(a[3] * linv3);
      }
    }
  } else {
    bf16* dst = (hf == 0) ? olat : P1;
    const int rbase = (hf == 0) ? (qt * 128) : (qt * 128 - 1024);
#pragma unroll
    for (int qb = 0; qb < 8; ++qb)
#pragma unroll
      for (int cfc = 0; cfc < 4; ++cfc) {
        const long base = (long)(rbase + qb * 16 + (hi << 2)) * 16384 + h * 512 + w * 64 + cfc * 16 + r16;
        v4f a = acc[qb * 4 + cfc];
        dst[base + 0 * 16384] = __float2bfloat16(a[0]);
        dst[base + 1 * 16384] = __float2bfloat16(a[1]);
        dst[base + 2 * 16384] = __float2bfloat16(a[2]);
        dst[base + 3 * 16384] = __float2bfloat16(a[3]);
      }
  }
}

// combine split partials for rows 1024..2047:
// O = (sA*OA + sB*OB) / (sA*lA + sB*lB), s* = exp(m* - max(mA,mB))
__global__ void combine_kernel(bf16* __restrict__ olat, const bf16* __restrict__ P1,
                               const float* __restrict__ mlb) {
  int gid = blockIdx.x * 256 + threadIdx.x;  // 1024*32*64
  int cg = gid & 63, h = (gid >> 6) & 31, r = gid >> 11;
  const float* m4 = mlb + ((r << 5) + h) * 4;
  float mA = m4[0], lA = m4[1], mB = m4[2], lB = m4[3];
  float m = fmaxf(mA, mB);
  float sA = __expf(mA - m), sB = __expf(mB - m);
  float inv = 1.0f / (sA * lA + sB * lB);
  sA *= inv; sB *= inv;
  long oa = (long)(1024 + r) * 16384 + h * 512 + cg * 8;
  long ob = (long)r * 16384 + h * 512 + cg * 8;
  v8s a = *(const v8s*)(olat + oa);
  v8s b = *(const v8s*)(P1 + ob);
  v8s o;
#pragma unroll
  for (int j = 0; j < 8; ++j)
    o[j] = (short)bfu(b2f(a[j]) * sA + b2f(b[j]) * sB);
  *(v8s*)(olat + oa) = o;
}

// ---------------- launch ----------------
// Workspace (peak 181.7 MB, temporally aliased; single stream => safe)

extern "C" void kernel_launch(void* const* d_in, const int* in_sizes, int n_in,
                              void* d_out, int out_size, void* d_ws, size_t ws_size,
                              hipStream_t stream) {
  const float* x = (const float*)d_in[0];
  const float* wq_a = (const float*)d_in[1];
  const float* q_norm_w = (const float*)d_in[2];
  const float* wq_b = (const float*)d_in[3];
  const float* wkv_a = (const float*)d_in[4];
  const float* kv_norm_w = (const float*)d_in[5];
  const float* wkv_b = (const float*)d_in[6];
  const float* wo = (const float*)d_in[7];
  char* ws = (char*)d_ws;

  float* cosb  = (float*)(ws + 0);
  float* sinb  = (float*)(ws + 262144);
  // long-lived
  bf16* qeffb  = (bf16*)(ws + 524288);      // 2048x32x576 (75.5MB), live rope_q..attn
  bf16* olat   = (bf16*)(ws + 76021760);    // 2048x32x512 (64MB), live attn..o-gemm
  bf16* keff   = (bf16*)(ws + 143130624);   // 2048x576, live norm..attn
  bf16* vTb    = (bf16*)(ws + 145489920);   // 512x2048 (2MB), live vtrans..attn
  bf16* P1b    = (bf16*)(ws + 147587072);   // 1024x32x512 (32MB), live attn..combine
  float* mlb   = (float*)(ws + 181141504);  // 1024x32x4 f32 (0.5MB); ends 181,665,792
  // pre-attention arena (inside olat region, dead before attn writes olat)
  bf16* xb     = (bf16*)(ws + 76021760);    // 2048x4096
  bf16* wqab   = (bf16*)(ws + 92798976);    // 1536x4096 } contiguous => fused
  bf16* wkvabp = (bf16*)(ws + 105381888);   // 640x4096  } N=2176 B matrix
  bf16* qakv   = (bf16*)(ws + 110624768);   // 2048x2176 fused qa|kv (8.9MB)
  bf16* qan    = (bf16*)(ws + 125829120);   // 2048x1536
  bf16* wqbb   = (bf16*)(ws + 76021760);    // 6144x1536 (after xb/wqab dead)
  bf16* qf     = (bf16*)(ws + 94896128);    // 2048x6144 (after qakv dead)
  bf16* wkvb1t = (bf16*)(ws + 76021760);    // 32x512x128 (after wqbb dead)
  // post-attention arena (inside qeffb region, dead after attn)
  bf16* wkvbv  = (bf16*)(ws + 524288);      // 32x128x512
  bf16* obuf   = (bf16*)(ws + 4718592);     // 2048x4096
  bf16* wob    = (bf16*)(ws + 21495808);    // 4096x4096

  // stage 1: casts + freqs
  cast_kernel<<<2048, 256, 0, stream>>>(x, xb, 2097152);
  cast_kernel<<<2048, 256, 0, stream>>>(wq_a, wqab, 1572864);
  cast_pad_kernel<<<2560, 256, 0, stream>>>(wkv_a, wkvabp);
  freqs_kernel<<<256, 256, 0, stream>>>(cosb, sinb);

  // stage 2: fused q-a + kv-a projection (N = 1536 + 640 = 2176, 272 blocks)
  gemm_bt<bf16><<<dim3(17, 16, 1), 256, 0, stream>>>(xb, wqab, qakv, 4096, 4096, 4096, 2176, 0, 0, 0);

  // stage 3: norms + k rope + V transpose
  rmsnorm_bf_kernel<<<2048, 256, 0, stream>>>(qakv, q_norm_w, qan, 1536, 2176, 1536);
  rmsnorm_bf_kernel<<<2048, 256, 0, stream>>>(qakv + 1536, kv_norm_w, keff, 512, 2176, 576);
  rope_kpe_kernel<<<256, 256, 0, stream>>>(qakv, cosb, sinb, keff);
  vtrans_kernel<<<64, 256, 0, stream>>>(keff, vTb);

  // stage 4: q up-projection (wqbb aliases xb/wqab; qf aliases qakv tail)
  cast_kernel<<<2048, 256, 0, stream>>>(wq_b, wqbb, 2359296);
  gemm_bt<bf16><<<dim3(48, 16, 1), 256, 0, stream>>>(qan, wqbb, qf, 1536, 1536, 1536, 6144, 0, 0, 0);

  // stage 5: q rope + latent projection (one-shot K=128 GEMM)
  rope_q_kernel<<<8192, 256, 0, stream>>>(qf, cosb, sinb, qeffb);
  wkvbt_kernel<<<128, 256, 0, stream>>>(wkv_b, wkvb1t);
  gemm_k128<<<dim3(4, 16, 32), 256, 0, stream>>>(qf, wkvb1t, qeffb,
      6144, 128, 18432, 192L, 65536L, 576L);

  // stage 6: attention (KV-split balanced, descending dispatch) + combine
  attn_kernel<<<dim3(32, 24), 512, 0, stream>>>(qeffb, keff, vTb, olat, P1b, mlb);
  combine_kernel<<<8192, 256, 0, stream>>>(olat, P1b, mlb);

  // stage 7: per-head V projection (wkvbv/obuf alias dead qeffb)
  wkvbv_kernel<<<2048, 256, 0, stream>>>(wkv_b, wkvbv);
  gemm_bt<bf16><<<dim3(1, 16, 32), 256, 0, stream>>>(olat, wkvbv, obuf,
      512, 16384, 512, 4096, 512L, 65536L, 128L);

  // stage 8: output projection
  cast_kernel<<<2048, 256, 0, stream>>>(wo, wob, 4194304);
  gemm_bt<float><<<dim3(32, 16, 1), 256, 0, stream>>>(obuf, wob, (float*)d_out,
      4096, 4096, 4096, 4096, 0, 0, 0);
}

// Round 17
// 631.070 us; speedup vs baseline: 1.1360x; 1.1360x over previous
//
#include <hip/hip_runtime.h>
#include <hip/hip_bf16.h>
#include <type_traits>

using bf16 = __hip_bfloat16;
typedef short v8s __attribute__((ext_vector_type(8)));
typedef float v4f __attribute__((ext_vector_type(4)));

#define DEV __device__ __forceinline__

constexpr float SCALE_ = 0.07216878364870322f;  // (128+64)^-0.5

DEV unsigned short bfu(float f) {
  bf16 h = __float2bfloat16(f);
  return __builtin_bit_cast(unsigned short, h);
}
DEV float b2f(short u) {
  unsigned int x = ((unsigned int)(unsigned short)u) << 16;
  return __builtin_bit_cast(float, x);
}

DEV void g2lds16(const void* g, void* l) {
  __builtin_amdgcn_global_load_lds(
      (const __attribute__((address_space(1))) unsigned int*)g,
      (__attribute__((address_space(3))) unsigned int*)l, 16, 0, 0);
}

// ---------------- elementwise / prep kernels ----------------

__global__ void cast_kernel(const float* __restrict__ in, bf16* __restrict__ out, int n4) {
  int i = blockIdx.x * 256 + threadIdx.x;
  int stride = gridDim.x * 256;
  for (; i < n4; i += stride) {
    float4 v = ((const float4*)in)[i];
    ushort4 u;
    u.x = bfu(v.x); u.y = bfu(v.y); u.z = bfu(v.z); u.w = bfu(v.w);
    ((ushort4*)out)[i] = u;
  }
}

// wkv_a (576,4096) f32 -> (640,4096) bf16 zero-padded
__global__ void cast_pad_kernel(const float* __restrict__ in, bf16* __restrict__ out) {
  int i = blockIdx.x * 256 + threadIdx.x;  // 655360 float4 groups
  float4 v = make_float4(0.f, 0.f, 0.f, 0.f);
  if (i < 589824) v = ((const float4*)in)[i];  // 576*4096/4
  ushort4 u;
  u.x = bfu(v.x); u.y = bfu(v.y); u.z = bfu(v.z); u.w = bfu(v.w);
  ((ushort4*)out)[i] = u;
}

// wkv_b nope-part transpose, coalesced 8x8 reg-block:
// out[h][c][d] = wkvb[(h*256+d)*512 + c], d<128, c<512.
__global__ void wkvbt_kernel(const float* __restrict__ wkvb, bf16* __restrict__ out) {
  int gid = blockIdx.x * 256 + threadIdx.x;  // 32*16*64
  int c8 = (gid & 63) * 8;
  int d8 = ((gid >> 6) & 15) * 8;
  int h = gid >> 10;
  float4 a[8][2];
#pragma unroll
  for (int r = 0; r < 8; ++r) {
    const float* p = wkvb + ((long)(h * 256 + d8 + r)) * 512 + c8;
    a[r][0] = *(const float4*)p;
    a[r][1] = *(const float4*)(p + 4);
  }
#pragma unroll
  for (int cc = 0; cc < 8; ++cc) {
    v8s o;
#pragma unroll
    for (int r = 0; r < 8; ++r) {
      float f = (cc < 4) ? ((const float*)&a[r][0])[cc] : ((const float*)&a[r][1])[cc - 4];
      o[r] = (short)bfu(f);
    }
    *(v8s*)(out + (long)h * 65536 + (c8 + cc) * 128 + d8) = o;
  }
}

// wkv_b v-part: out[h*128+d][c] = wkv_b[(h*256+128+d)][c], bf16
__global__ void wkvbv_kernel(const float* __restrict__ wkvb, bf16* __restrict__ out) {
  int i = blockIdx.x * 256 + threadIdx.x;  // 524288 float4 groups
  int c4 = i & 127, d = (i >> 7) & 127, h = i >> 14;
  float4 v = *(const float4*)(wkvb + ((long)(h * 256 + 128 + d)) * 512 + c4 * 4);
  ushort4 u;
  u.x = bfu(v.x); u.y = bfu(v.y); u.z = bfu(v.z); u.w = bfu(v.w);
  *(ushort4*)(out + ((long)(h * 128 + d)) * 512 + c4 * 4) = u;
}

__global__ void freqs_kernel(float* __restrict__ cosb, float* __restrict__ sinb) {
  int t = blockIdx.x * 256 + threadIdx.x;  // 2048*32
  int s = t >> 5, i = t & 31;
  float inv = powf(10000.0f, -(float)(2 * i) / 64.0f);
  float f = (float)s * inv;
  cosb[t] = cosf(f);
  sinb[t] = sinf(f);
}

// rmsnorm over bf16 rows, f32 weight, bf16 out
__global__ void rmsnorm_bf_kernel(const bf16* __restrict__ in, const float* __restrict__ w,
                                  bf16* __restrict__ out, int L, int ldin, int ldout) {
  int row = blockIdx.x;
  const bf16* x = in + (long)row * ldin;
  int L8 = L >> 3;
  float ss = 0.f;
  for (int i = threadIdx.x; i < L8; i += 256) {
    v8s v = *(const v8s*)(x + i * 8);
#pragma unroll
    for (int j = 0; j < 8; ++j) { float f = b2f(v[j]); ss += f * f; }
  }
#pragma unroll
  for (int d = 1; d < 64; d <<= 1) ss += __shfl_xor(ss, d);
  __shared__ float red[4];
  if ((threadIdx.x & 63) == 0) red[threadIdx.x >> 6] = ss;
  __syncthreads();
  float r = rsqrtf((red[0] + red[1] + red[2] + red[3]) / (float)L + 1e-6f);
  bf16* o = out + (long)row * ldout;
  for (int i = threadIdx.x; i < L8; i += 256) {
    v8s v = *(const v8s*)(x + i * 8);
    v8s u;
#pragma unroll
    for (int j = 0; j < 8; ++j)
      u[j] = (short)bfu(b2f(v[j]) * r * w[i * 8 + j]);
    *(v8s*)(o + i * 8) = u;
  }
}

// k_pe rope: qa_kv (S,2176) bf16 cols 2048..2111 -> keff (S,576) cols 512..575
__global__ void rope_kpe_kernel(const bf16* __restrict__ qakv, const float* __restrict__ cosb,
                                const float* __restrict__ sinb, bf16* __restrict__ keff) {
  int t = blockIdx.x * 256 + threadIdx.x;  // 2048*32
  int s = t >> 5, i = t & 31;
  const bf16* p = qakv + (long)s * 2176 + 2048;
  float x0 = __bfloat162float(p[2 * i]), x1 = __bfloat162float(p[2 * i + 1]);
  float c = cosb[t], sn = sinb[t];
  bf16* o = keff + (long)s * 576 + 512;
  o[2 * i] = __float2bfloat16(x0 * c - x1 * sn);
  o[2 * i + 1] = __float2bfloat16(x0 * sn + x1 * c);
}

// q_pe rope: qf (S,32,192) cols 128..191 -> qeff (S,32,576) cols 512..575
__global__ void rope_q_kernel(const bf16* __restrict__ qf, const float* __restrict__ cosb,
                              const float* __restrict__ sinb, bf16* __restrict__ qeff) {
  int t = blockIdx.x * 256 + threadIdx.x;  // S*H*32
  int i = t & 31, h = (t >> 5) & 31, s = t >> 10;
  const bf16* p = qf + (long)s * 6144 + h * 192 + 128;
  float x0 = __bfloat162float(p[2 * i]), x1 = __bfloat162float(p[2 * i + 1]);
  float c = cosb[s * 32 + i], sn = sinb[s * 32 + i];
  bf16* o = qeff + (long)s * 18432 + h * 576 + 512;
  o[2 * i] = __float2bfloat16(x0 * c - x1 * sn);
  o[2 * i + 1] = __float2bfloat16(x0 * sn + x1 * c);
}

// vT[c][t] = keff[t][c] for c<512 (latent V, post-rmsnorm). 8x8 reg transpose.
__global__ void vtrans_kernel(const bf16* __restrict__ keff, bf16* __restrict__ vT) {
  int gid = blockIdx.x * 256 + threadIdx.x;  // 16384 threads
  int t8 = (gid & 255) * 8, c8 = (gid >> 8) * 8;
  v8s in[8];
#pragma unroll
  for (int r = 0; r < 8; ++r)
    in[r] = *(const v8s*)(keff + (long)(t8 + r) * 576 + c8);
#pragma unroll
  for (int cc = 0; cc < 8; ++cc) {
    v8s o;
#pragma unroll
    for (int r = 0; r < 8; ++r) o[r] = in[r][cc];
    *(v8s*)(vT + (long)(c8 + cc) * 2048 + t8) = o;
  }
}

// ---------------- GEMM: C = A @ B^T, A (M,K) bf16, B (N,K) bf16 ----------------
// BK=64, XOR slot-swizzle (gemm_k128's verified pattern: 8 slots/row,
// slot ^= row&7 -> b128 reads bank-spread). Barriers per K halved vs BK=32;
// LDS 32KB -> 3 blocks/CU preserved.
template <typename OutT>
__global__ __launch_bounds__(256, 3) void gemm_bt(
    const bf16* __restrict__ A, const bf16* __restrict__ B, OutT* __restrict__ C,
    int K, int lda, int ldb, int ldc, long sA, long sB, long sC) {
  __shared__ bf16 lA[8192];
  __shared__ bf16 lB[8192];
  const int tid = threadIdx.x;
  const int lane = tid & 63;
  const int w = tid >> 6, wm = w >> 1, wn = w & 1;
  const int r16 = lane & 15, hi = lane >> 4;
  const bf16* Ab = A + (long)blockIdx.z * sA + (long)blockIdx.y * 128 * lda;
  const bf16* Bb = B + (long)blockIdx.z * sB + (long)blockIdx.x * 128 * ldb;
  v4f acc[4][4] = {};
  for (int k0 = 0; k0 < K; k0 += 64) {
    __syncthreads();
#pragma unroll
    for (int it = 0; it < 4; ++it) {
      int D = it * 256 + tid;       // slot 0..1023; 8 slots (128B) per row
      int row = D >> 3, sl = D & 7;
      int gs = sl ^ (row & 7);      // pre-swizzled source slot
      g2lds16(Ab + (long)row * lda + k0 + gs * 8, (char*)lA + (it * 256 + w * 64) * 16);
      g2lds16(Bb + (long)row * ldb + k0 + gs * 8, (char*)lB + (it * 256 + w * 64) * 16);
    }
    __syncthreads();
#pragma unroll
    for (int kk = 0; kk < 2; ++kk) {
      v8s af[4], bfr[4];
#pragma unroll
      for (int mi = 0; mi < 4; ++mi) {
        int r = wm * 64 + mi * 16 + r16;
        af[mi] = *(const v8s*)((const char*)lA + (r * 8 + ((kk * 4 + hi) ^ (r & 7))) * 16);
      }
#pragma unroll
      for (int ni = 0; ni < 4; ++ni) {
        int r = wn * 64 + ni * 16 + r16;
        bfr[ni] = *(const v8s*)((const char*)lB + (r * 8 + ((kk * 4 + hi) ^ (r & 7))) * 16);
      }
      __builtin_amdgcn_s_setprio(1);
#pragma unroll
      for (int mi = 0; mi < 4; ++mi)
#pragma unroll
        for (int ni = 0; ni < 4; ++ni)
          acc[mi][ni] = __builtin_amdgcn_mfma_f32_16x16x32_bf16(af[mi], bfr[ni], acc[mi][ni], 0, 0, 0);
      __builtin_amdgcn_s_setprio(0);
    }
  }
  OutT* Cb = C + (long)blockIdx.z * sC + (long)(blockIdx.y * 128) * ldc + blockIdx.x * 128;
  const int cr = hi << 2;
#pragma unroll
  for (int mi = 0; mi < 4; ++mi)
#pragma unroll
    for (int ni = 0; ni < 4; ++ni)
#pragma unroll
      for (int j = 0; j < 4; ++j) {
        long idx = (long)(wm * 64 + mi * 16 + cr + j) * ldc + wn * 64 + ni * 16 + r16;
        float v = acc[mi][ni][j];
        if constexpr (std::is_same<OutT, float>::value) Cb[idx] = v;
        else Cb[idx] = __float2bfloat16(v);
      }
}

// ---------------- GEMM K=128 one-shot: C = A @ B^T, single staging pass ----
__global__ __launch_bounds__(256, 2) void gemm_k128(
    const bf16* __restrict__ A, const bf16* __restrict__ B, bf16* __restrict__ C,
    int lda, int ldb, int ldc, long sA, long sB, long sC) {
  __shared__ bf16 lA[16384];
  __shared__ bf16 lB[16384];
  const int tid = threadIdx.x;
  const int lane = tid & 63;
  const int w = tid >> 6, wm = w >> 1, wn = w & 1;
  const int r16 = lane & 15, hi = lane >> 4;
  const bf16* Ab = A + (long)blockIdx.z * sA + (long)blockIdx.y * 128 * lda;
  const bf16* Bb = B + (long)blockIdx.z * sB + (long)blockIdx.x * 128 * ldb;
#pragma unroll
  for (int it = 0; it < 8; ++it) {
    int D = it * 256 + tid;       // slot 0..2047; 16 slots (256B) per row
    int row = D >> 4, sl = D & 15;
    int gs = sl ^ (row & 7);      // pre-swizzled source slot
    g2lds16(Ab + (long)row * lda + gs * 8, (char*)lA + (it * 256 + w * 64) * 16);
    g2lds16(Bb + (long)row * ldb + gs * 8, (char*)lB + (it * 256 + w * 64) * 16);
  }
  __syncthreads();
  v4f acc[4][4] = {};
#pragma unroll
  for (int kk = 0; kk < 4; ++kk) {
    v8s af[4], bfr[4];
#pragma unroll
    for (int mi = 0; mi < 4; ++mi) {
      int r = wm * 64 + mi * 16 + r16;
      af[mi] = *(const v8s*)((const char*)lA + (r * 16 + ((kk * 4 + hi) ^ (r & 7))) * 16);
    }
#pragma unroll
    for (int ni = 0; ni < 4; ++ni) {
      int r = wn * 64 + ni * 16 + r16;
      bfr[ni] = *(const v8s*)((const char*)lB + (r * 16 + ((kk * 4 + hi) ^ (r & 7))) * 16);
    }
    __builtin_amdgcn_s_setprio(1);
#pragma unroll
    for (int mi = 0; mi < 4; ++mi)
#pragma unroll
      for (int ni = 0; ni < 4; ++ni)
        acc[mi][ni] = __builtin_amdgcn_mfma_f32_16x16x32_bf16(af[mi], bfr[ni], acc[mi][ni], 0, 0, 0);
    __builtin_amdgcn_s_setprio(0);
  }
  bf16* Cb = C + (long)blockIdx.z * sC + (long)(blockIdx.y * 128) * ldc + blockIdx.x * 128;
  const int cr = hi << 2;
#pragma unroll
  for (int mi = 0; mi < 4; ++mi)
#pragma unroll
    for (int ni = 0; ni < 4; ++ni)
#pragma unroll
      for (int j = 0; j < 4; ++j) {
        long idx = (long)(wm * 64 + mi * 16 + cr + j) * ldc + wn * 64 + ni * 16 + r16;
        Cb[idx] = __float2bfloat16(acc[mi][ni][j]);
      }
}

// ---------------- causal flash attention (swapped-QK, KV-split balanced) ----
// grid (32 heads, 24 units), 512 thr, 8 waves, Q-tile 128. Round-12 design
// (row-split PV + shfl P redistribution): col-split PV refuted round 16,
// V-from-L2 refuted rounds 4/14.
__device__ const signed char U_QT[24] = {15,15,7,14,14,13,13,6,12,12,11,11,5,10,10,9,9,4,8,8,3,2,1,0};
__device__ const signed char U_HF[24] = {0,1,-1,0,1,0,1,-1,0,1,0,1,-1,0,1,0,1,-1,0,1,-1,-1,-1,-1};

__global__ __launch_bounds__(512, 2) void attn_kernel(
    const bf16* __restrict__ qeff, const bf16* __restrict__ keff,
    const bf16* __restrict__ vT, bf16* __restrict__ olat,
    bf16* __restrict__ P1, float* __restrict__ mlb) {
  __shared__ __align__(16) bf16 kl[32 * 576];  // 36864 B
  __shared__ __align__(16) bf16 vl[512 * 32];  // 32768 B
  const int tid = threadIdx.x, lane = tid & 63, w = tid >> 6;
  const int r16 = lane & 15, hi = lane >> 4;
  const int kg = hi << 3, cr = hi << 2;
  const int h = blockIdx.x;
  const int u = blockIdx.y;
  const int qt = U_QT[u];
  const int hf = U_HF[u];
  const int nch = 4 * qt + 4;
  const int kc0 = (hf == 1) ? (nch >> 1) : 0;
  const int kc1 = (hf == 0) ? (nch >> 1) : nch;
  const int qrow = qt * 128 + w * 16 + r16;
  const int rb = r16 & 7;

  const long qbase = (long)qrow * 18432 + h * 576;
  v8s qreg[18];
#pragma unroll
  for (int kk = 0; kk < 18; ++kk)
    qreg[kk] = __builtin_nontemporal_load((const v8s*)(qeff + qbase + kk * 32 + kg));

  v4f acc[32] = {};
  float mrow = -1e30f, lrow = 0.f;

  // staging helpers (16B slots; K: 72 slots/row, V: 4 slots/row)
  auto stageK = [&](int t0) {
#pragma unroll
    for (int it = 0; it < 5; ++it) {
      int D = it * 512 + tid;           // 0..2303 (last iter: waves 0-3 only)
      if (D < 2304) {
        int row = D / 72;
        int gg = D - row * 72;
        int gs = gg ^ (row & 7);        // pre-swizzled source slot
        g2lds16(keff + (long)(t0 + row) * 576 + gs * 8,
                (char*)kl + (it * 512 + w * 64) * 16);
      }
    }
  };
  auto stageV = [&](int t0) {
#pragma unroll
    for (int it = 0; it < 4; ++it) {
      int D = it * 512 + tid;           // 0..2047
      int row = D >> 2;
      int s = (D & 3) ^ ((row >> 1) & 3);
      g2lds16(vT + (long)row * 2048 + t0 + s * 8,
              (char*)vl + (it * 512 + w * 64) * 16);
    }
  };

  stageK(kc0 * 32);
  __syncthreads();

  for (int kc = kc0; kc < kc1; ++kc) {
    const int t0 = kc * 32;
    stageV(t0);  // drains at mid barrier (hidden under QK+softmax)

    // ---- S^T = K Q^T from kl (swizzled b128 reads, 2-way free) ----
    const char* kb = (const char*)kl;
    v4f sf0 = {}, sf1 = {};
    __builtin_amdgcn_s_setprio(1);
#pragma unroll
    for (int kk = 0; kk < 18; ++kk) {
      int so = ((kk * 4 + hi) ^ rb) << 4;
      v8s b0 = *(const v8s*)(kb + r16 * 1152 + so);
      v8s b1 = *(const v8s*)(kb + (16 + r16) * 1152 + so);
      sf0 = __builtin_amdgcn_mfma_f32_16x16x32_bf16(b0, qreg[kk], sf0, 0, 0, 0);
      sf1 = __builtin_amdgcn_mfma_f32_16x16x32_bf16(b1, qreg[kk], sf1, 0, 0, 0);
    }
    __builtin_amdgcn_s_setprio(0);
    // ---- mask + per-lane softmax (q = qrow) ----
    float s0[4], s1[4];
#pragma unroll
    for (int j = 0; j < 4; ++j) { s0[j] = sf0[j] * SCALE_; s1[j] = sf1[j] * SCALE_; }
    if (kc >= 4 * qt) {
#pragma unroll
      for (int j = 0; j < 4; ++j) {
        if (t0 + cr + j > qrow) s0[j] = -1e30f;
        if (t0 + 16 + cr + j > qrow) s1[j] = -1e30f;
      }
    }
    float mx = fmaxf(fmaxf(fmaxf(s0[0], s0[1]), fmaxf(s0[2], s0[3])),
                     fmaxf(fmaxf(s1[0], s1[1]), fmaxf(s1[2], s1[3])));
    mx = fmaxf(mx, __shfl_xor(mx, 16));
    mx = fmaxf(mx, __shfl_xor(mx, 32));
    // defer-max: rescale only when the running max grew by > 8
    if (!__all(mx <= mrow + 8.0f)) {
      float mn = fmaxf(mrow, mx);
      float alpha = __expf(mrow - mn);
      mrow = mn;
      lrow *= alpha;
      float af0 = __shfl(alpha, cr + 0), af1 = __shfl(alpha, cr + 1);
      float af2 = __shfl(alpha, cr + 2), af3 = __shfl(alpha, cr + 3);
#pragma unroll
      for (int c = 0; c < 32; ++c) {
        acc[c][0] *= af0; acc[c][1] *= af1; acc[c][2] *= af2; acc[c][3] *= af3;
      }
    }
    float p0[4], p1[4];
#pragma unroll
    for (int j = 0; j < 4; ++j) {
      p0[j] = __expf(s0[j] - mrow);
      p1[j] = __expf(s1[j] - mrow);
    }
    float rs = (p0[0] + p0[1]) + (p0[2] + p0[3]) + (p1[0] + p1[1]) + (p1[2] + p1[3]);
    rs += __shfl_xor(rs, 16);
    rs += __shfl_xor(rs, 32);
    lrow += rs;
    // ---- pack P to bf16 pairs and redistribute to PV A-frag ----
    int u0 = (int)((unsigned)bfu(p0[0]) | ((unsigned)bfu(p0[1]) << 16));
    int u1 = (int)((unsigned)bfu(p0[2]) | ((unsigned)bfu(p0[3]) << 16));
    int v0 = (int)((unsigned)bfu(p1[0]) | ((unsigned)bfu(p1[1]) << 16));
    int v1 = (int)((unsigned)bfu(p1[2]) | ((unsigned)bfu(p1[3]) << 16));
    const int L1 = r16 + 32 * (hi & 1);
    const int L2 = L1 + 16;
    const bool lo = hi < 2;
    int d0a = __shfl(u0, L1), d0b = __shfl(v0, L1);
    int d1a = __shfl(u1, L1), d1b = __shfl(v1, L1);
    int d2a = __shfl(u0, L2), d2b = __shfl(v0, L2);
    int d3a = __shfl(u1, L2), d3b = __shfl(v1, L2);
    int4 pw = make_int4(lo ? d0a : d0b, lo ? d1a : d1b, lo ? d2a : d2b, lo ? d3a : d3b);
    v8s ap = __builtin_bit_cast(v8s, pw);

    __syncthreads();  // kl QK reads done (all waves); stageV drained
    if (kc + 1 < kc1) stageK(t0 + 32);  // overwrite kl; drains at loop-end barrier

    // ---- PV from vl (swizzled b128 reads, 2-way free) ----
    __builtin_amdgcn_s_setprio(1);
#pragma unroll
    for (int c = 0; c < 32; ++c) {
      const int vrow = c * 16 + r16;
      const int vsw = (hi ^ ((vrow >> 1) & 3)) << 4;
      v8s bv = *(const v8s*)((const char*)vl + vrow * 64 + vsw);
      acc[c] = __builtin_amdgcn_mfma_f32_16x16x32_bf16(ap, bv, acc[c], 0, 0, 0);
    }
    __builtin_amdgcn_s_setprio(0);
    __syncthreads();  // vl reads done; stageK drained -> kl ready
  }
  // ---- epilogue ----
  if (hf < 0) {
    // unsplit: normalize + store
    float linv0 = 1.0f / __shfl(lrow, cr + 0);
    float linv1 = 1.0f / __shfl(lrow, cr + 1);
    float linv2 = 1.0f / __shfl(lrow, cr + 2);
    float linv3 = 1.0f / __shfl(lrow, cr + 3);
    const long ob = (long)(qt * 128 + w * 16 + cr) * 16384 + h * 512 + r16;
#pragma unroll
    for (int c = 0; c < 32; ++c) {
      olat[ob + 0 * 16384 + c * 16] = __float2bfloat16(acc[c][0] * linv0);
      olat[ob + 1 * 16384 + c * 16] = __float2bfloat16(acc[c][1] * linv1);
      olat[ob + 2 * 16384 + c * 16] = __float2bfloat16(acc[c][2] * linv2);
      olat[ob + 3 * 16384 + c * 16] = __float2bfloat16(acc[c][3] * linv3);
    }
  } else {
    // split: store unnormalized partial + (m,l); rows are >= 1024 (qt >= 8)
    if (hi == 0) {
      float* mr = mlb + (((qrow - 1024) << 5) + h) * 4 + hf * 2;
      mr[0] = mrow;
      mr[1] = lrow;
    }
    bf16* dst = (hf == 0) ? olat : P1;
    const int rbase = (hf == 0) ? (qt * 128) : (qt * 128 - 1024);
    const long ob = (long)(rbase + w * 16 + cr) * 16384 + h * 512 + r16;
#pragma unroll
    for (int c = 0; c < 32; ++c) {
      dst[ob + 0 * 16384 + c * 16] = __float2bfloat16(acc[c][0]);
      dst[ob + 1 * 16384 + c * 16] = __float2bfloat16(acc[c][1]);
      dst[ob + 2 * 16384 + c * 16] = __float2bfloat16(acc[c][2]);
      dst[ob + 3 * 16384 + c * 16] = __float2bfloat16(acc[c][3]);
    }
  }
}

// combine split partials for rows 1024..2047:
// O = (sA*OA + sB*OB) / (sA*lA + sB*lB), s* = exp(m* - max(mA,mB))
__global__ void combine_kernel(bf16* __restrict__ olat, const bf16* __restrict__ P1,
                               const float* __restrict__ mlb) {
  int gid = blockIdx.x * 256 + threadIdx.x;  // 1024*32*64
  int cg = gid & 63, h = (gid >> 6) & 31, r = gid >> 11;
  const float* m4 = mlb + ((r << 5) + h) * 4;
  float mA = m4[0], lA = m4[1], mB = m4[2], lB = m4[3];
  float m = fmaxf(mA, mB);
  float sA = __expf(mA - m), sB = __expf(mB - m);
  float inv = 1.0f / (sA * lA + sB * lB);
  sA *= inv; sB *= inv;
  long oa = (long)(1024 + r) * 16384 + h * 512 + cg * 8;
  long ob = (long)r * 16384 + h * 512 + cg * 8;
  v8s a = *(const v8s*)(olat + oa);
  v8s b = *(const v8s*)(P1 + ob);
  v8s o;
#pragma unroll
  for (int j = 0; j < 8; ++j)
    o[j] = (short)bfu(b2f(a[j]) * sA + b2f(b[j]) * sB);
  *(v8s*)(olat + oa) = o;
}

// ---------------- launch ----------------
// Workspace (peak 181.7 MB, temporally aliased; single stream => safe)

extern "C" void kernel_launch(void* const* d_in, const int* in_sizes, int n_in,
                              void* d_out, int out_size, void* d_ws, size_t ws_size,
                              hipStream_t stream) {
  const float* x = (const float*)d_in[0];
  const float* wq_a = (const float*)d_in[1];
  const float* q_norm_w = (const float*)d_in[2];
  const float* wq_b = (const float*)d_in[3];
  const float* wkv_a = (const float*)d_in[4];
  const float* kv_norm_w = (const float*)d_in[5];
  const float* wkv_b = (const float*)d_in[6];
  const float* wo = (const float*)d_in[7];
  char* ws = (char*)d_ws;

  float* cosb  = (float*)(ws + 0);
  float* sinb  = (float*)(ws + 262144);
  // long-lived
  bf16* qeffb  = (bf16*)(ws + 524288);      // 2048x32x576 (75.5MB), live rope_q..attn
  bf16* olat   = (bf16*)(ws + 76021760);    // 2048x32x512 (64MB), live attn..o-gemm
  bf16* keff   = (bf16*)(ws + 143130624);   // 2048x576, live norm..attn
  bf16* vTb    = (bf16*)(ws + 145489920);   // 512x2048 (2MB), live vtrans..attn
  bf16* P1b    = (bf16*)(ws + 147587072);   // 1024x32x512 (32MB), live attn..combine
  float* mlb   = (float*)(ws + 181141504);  // 1024x32x4 f32 (0.5MB); ends 181,665,792
  // pre-attention arena (inside olat region, dead before attn writes olat)
  bf16* xb     = (bf16*)(ws + 76021760);    // 2048x4096
  bf16* wqab   = (bf16*)(ws + 92798976);    // 1536x4096 } contiguous => fused
  bf16* wkvabp = (bf16*)(ws + 105381888);   // 640x4096  } N=2176 B matrix
  bf16* qakv   = (bf16*)(ws + 110624768);   // 2048x2176 fused qa|kv (8.9MB)
  bf16* qan    = (bf16*)(ws + 125829120);   // 2048x1536
  bf16* wqbb   = (bf16*)(ws + 76021760);    // 6144x1536 (after xb/wqab dead)
  bf16* qf     = (bf16*)(ws + 94896128);    // 2048x6144 (after qakv dead)
  bf16* wkvb1t = (bf16*)(ws + 76021760);    // 32x512x128 (after wqbb dead)
  // post-attention arena (inside qeffb region, dead after attn)
  bf16* wkvbv  = (bf16*)(ws + 524288);      // 32x128x512
  bf16* obuf   = (bf16*)(ws + 4718592);     // 2048x4096
  bf16* wob    = (bf16*)(ws + 21495808);    // 4096x4096

  // stage 1: casts + freqs
  cast_kernel<<<2048, 256, 0, stream>>>(x, xb, 2097152);
  cast_kernel<<<2048, 256, 0, stream>>>(wq_a, wqab, 1572864);
  cast_pad_kernel<<<2560, 256, 0, stream>>>(wkv_a, wkvabp);
  freqs_kernel<<<256, 256, 0, stream>>>(cosb, sinb);

  // stage 2: fused q-a + kv-a projection (N = 1536 + 640 = 2176, 272 blocks)
  gemm_bt<bf16><<<dim3(17, 16, 1), 256, 0, stream>>>(xb, wqab, qakv, 4096, 4096, 4096, 2176, 0, 0, 0);

  // stage 3: norms + k rope + V transpose
  rmsnorm_bf_kernel<<<2048, 256, 0, stream>>>(qakv, q_norm_w, qan, 1536, 2176, 1536);
  rmsnorm_bf_kernel<<<2048, 256, 0, stream>>>(qakv + 1536, kv_norm_w, keff, 512, 2176, 576);
  rope_kpe_kernel<<<256, 256, 0, stream>>>(qakv, cosb, sinb, keff);
  vtrans_kernel<<<64, 256, 0, stream>>>(keff, vTb);

  // stage 4: q up-projection (wqbb aliases xb/wqab; qf aliases qakv tail)
  cast_kernel<<<2048, 256, 0, stream>>>(wq_b, wqbb, 2359296);
  gemm_bt<bf16><<<dim3(48, 16, 1), 256, 0, stream>>>(qan, wqbb, qf, 1536, 1536, 1536, 6144, 0, 0, 0);

  // stage 5: q rope + latent projection (one-shot K=128 GEMM)
  rope_q_kernel<<<8192, 256, 0, stream>>>(qf, cosb, sinb, qeffb);
  wkvbt_kernel<<<128, 256, 0, stream>>>(wkv_b, wkvb1t);
  gemm_k128<<<dim3(4, 16, 32), 256, 0, stream>>>(qf, wkvb1t, qeffb,
      6144, 128, 18432, 192L, 65536L, 576L);

  // stage 6: attention (KV-split balanced, descending dispatch) + combine
  attn_kernel<<<dim3(32, 24), 512, 0, stream>>>(qeffb, keff, vTb, olat, P1b, mlb);
  combine_kernel<<<8192, 256, 0, stream>>>(olat, P1b, mlb);

  // stage 7: per-head V projection (wkvbv/obuf alias dead qeffb)
  wkvbv_kernel<<<2048, 256, 0, stream>>>(wkv_b, wkvbv);
  gemm_bt<bf16><<<dim3(1, 16, 32), 256, 0, stream>>>(olat, wkvbv, obuf,
      512, 16384, 512, 4096, 512L, 65536L, 128L);

  // stage 8: output projection
  cast_kernel<<<2048, 256, 0, stream>>>(wo, wob, 4194304);
  gemm_bt<float><<<dim3(32, 16, 1), 256, 0, stream>>>(obuf, wob, (float*)d_out,
      4096, 4096, 4096, 4096, 0, 0, 0);
}